// Round 1
// baseline (2952.140 us; speedup 1.0000x reference)
//
#include <hip/hip_runtime.h>

#define NN 50000
#define NE 800000
#define D 128

// ---------------- degree / norm precompute ----------------

__global__ __launch_bounds__(256) void k_deg_init(float* __restrict__ deg, int n) {
    int i = blockIdx.x * 256 + threadIdx.x;
    if (i < n) deg[i] = 1.0f;  // self-loop weight
}

__global__ __launch_bounds__(256) void k_deg_acc(const int* __restrict__ dst,
                                                 const float* __restrict__ ew,
                                                 float* __restrict__ deg, int e) {
    int i = blockIdx.x * 256 + threadIdx.x;
    if (i < e) atomicAdd(&deg[dst[i]], ew[i]);
}

__global__ __launch_bounds__(256) void k_norm(const int* __restrict__ src,
                                              const int* __restrict__ dst,
                                              const float* __restrict__ ew,
                                              const float* __restrict__ deg,
                                              float* __restrict__ norm, int e) {
    int i = blockIdx.x * 256 + threadIdx.x;
    if (i < e) {
        float ds = deg[src[i]];
        float dd = deg[dst[i]];
        norm[i] = rsqrtf(ds) * ew[i] * rsqrtf(dd);
    }
}

// ---------------- GEMM: h = A @ W, agg = dinv^2 * h (self-loop seed) ----------------
// Block: 256 threads, 32 nodes per block. x-tile staged in LDS (16 KB).
// Thread (g = tid>>7, c = tid&127) computes h[n0+g*16+i][c] for i in 0..15.

__global__ __launch_bounds__(256) void k_gemm(const float* __restrict__ A,
                                              const float* __restrict__ W,
                                              const float* __restrict__ deg,
                                              float* __restrict__ h,
                                              float* __restrict__ agg, int n) {
    __shared__ float xs[32][D];
    const int n0 = blockIdx.x * 32;
    const int tid = threadIdx.x;

#pragma unroll
    for (int i = 0; i < 16; ++i) {
        int idx = tid + i * 256;
        int r = idx >> 7, c = idx & 127;
        int nn = n0 + r;
        xs[r][c] = (nn < n) ? A[nn * D + c] : 0.0f;
    }
    __syncthreads();

    const int c = tid & 127;
    const int g = tid >> 7;

    float acc[16];
#pragma unroll
    for (int i = 0; i < 16; ++i) acc[i] = 0.0f;

    for (int k = 0; k < D; k += 4) {
        float w0 = W[(k + 0) * D + c];
        float w1 = W[(k + 1) * D + c];
        float w2 = W[(k + 2) * D + c];
        float w3 = W[(k + 3) * D + c];
#pragma unroll
        for (int i = 0; i < 16; ++i) {
            float4 xv = *(const float4*)&xs[g * 16 + i][k];
            acc[i] += xv.x * w0 + xv.y * w1 + xv.z * w2 + xv.w * w3;
        }
    }

#pragma unroll
    for (int i = 0; i < 16; ++i) {
        int nn = n0 + g * 16 + i;
        if (nn < n) {
            float di = rsqrtf(deg[nn]);
            float v = acc[i];
            h[nn * D + c] = v;
            agg[nn * D + c] = di * di * v;  // self-loop term; also zero-inits agg
        }
    }
}

// ---------------- edge aggregation: agg[dst] += norm * h[src] ----------------
// 32 threads per edge, each handling 4 consecutive features (float4 gather).

__global__ __launch_bounds__(256) void k_edge_agg(const int* __restrict__ src,
                                                  const int* __restrict__ dst,
                                                  const float* __restrict__ norm,
                                                  const float* __restrict__ h,
                                                  float* __restrict__ agg, int e) {
    int t = blockIdx.x * 256 + threadIdx.x;
    int ei = t >> 5;
    if (ei >= e) return;
    int f = (t & 31) * 4;
    int s = src[ei];
    int d = dst[ei];
    float cn = norm[ei];
    float4 hv = *(const float4*)&h[s * D + f];
    float* ap = &agg[d * D + f];
    atomicAdd(ap + 0, cn * hv.x);
    atomicAdd(ap + 1, cn * hv.y);
    atomicAdd(ap + 2, cn * hv.z);
    atomicAdd(ap + 3, cn * hv.w);
}

// ---------------- x1 = relu(agg + b) ----------------

__global__ __launch_bounds__(256) void k_relu_bias(const float* __restrict__ agg,
                                                   const float* __restrict__ b,
                                                   float* __restrict__ xo, int total4) {
    int i = blockIdx.x * 256 + threadIdx.x;
    if (i >= total4) return;
    int base = i * 4;
    int f = base & (D - 1);
    float4 v = *(const float4*)&agg[base];
    v.x = fmaxf(v.x + b[f + 0], 0.0f);
    v.y = fmaxf(v.y + b[f + 1], 0.0f);
    v.z = fmaxf(v.z + b[f + 2], 0.0f);
    v.w = fmaxf(v.w + b[f + 3], 0.0f);
    *(float4*)&xo[base] = v;
}

// ---------------- finalize: out[n][f] = (x1[n][f], relu(agg2+b2)) interleaved ----------------

__global__ __launch_bounds__(256) void k_finalize(const float* __restrict__ x1,
                                                  const float* __restrict__ agg2,
                                                  const float* __restrict__ b2,
                                                  float* __restrict__ out, int total) {
    int i = blockIdx.x * 256 + threadIdx.x;
    if (i >= total) return;
    int f = i & (D - 1);
    float x2 = fmaxf(agg2[i] + b2[f], 0.0f);
    float2 o;
    o.x = x1[i];
    o.y = x2;
    ((float2*)out)[i] = o;
}

extern "C" void kernel_launch(void* const* d_in, const int* in_sizes, int n_in,
                              void* d_out, int out_size, void* d_ws, size_t ws_size,
                              hipStream_t stream) {
    const float* x  = (const float*)d_in[0];
    const int*   ei = (const int*)d_in[1];
    const float* ew = (const float*)d_in[2];
    const float* W1 = (const float*)d_in[3];
    const float* b1 = (const float*)d_in[4];
    const float* W2 = (const float*)d_in[5];
    const float* b2 = (const float*)d_in[6];
    float* out = (float*)d_out;

    const int* src = ei;
    const int* dst = ei + NE;

    // workspace layout (all 256B-aligned)
    char* w = (char*)d_ws;
    auto take = [&](size_t bytes) {
        char* p = w;
        w += (bytes + 255) & ~(size_t)255;
        return p;
    };
    float* deg    = (float*)take((size_t)NN * 4);
    float* norm   = (float*)take((size_t)NE * 4);
    float* hbuf   = (float*)take((size_t)NN * D * 4);
    float* aggbuf = (float*)take((size_t)NN * D * 4);
    float* x1     = (float*)take((size_t)NN * D * 4);

    const int nThreads = 256;
    const int nBlkN   = (NN + 255) / 256;
    const int nBlkE   = (NE + 255) / 256;
    const int nBlkG   = (NN + 31) / 32;
    const int nBlkAgg = (NE * 32 + 255) / 256;  // 100000
    const int nBlkR   = (NN * D / 4 + 255) / 256;
    const int nBlkF   = (NN * D + 255) / 256;

    // degree + norm (shared by both layers)
    k_deg_init<<<nBlkN, nThreads, 0, stream>>>(deg, NN);
    k_deg_acc<<<nBlkE, nThreads, 0, stream>>>(dst, ew, deg, NE);
    k_norm<<<nBlkE, nThreads, 0, stream>>>(src, dst, ew, deg, norm, NE);

    // layer 1
    k_gemm<<<nBlkG, nThreads, 0, stream>>>(x, W1, deg, hbuf, aggbuf, NN);
    k_edge_agg<<<nBlkAgg, nThreads, 0, stream>>>(src, dst, norm, hbuf, aggbuf, NE);
    k_relu_bias<<<nBlkR, nThreads, 0, stream>>>(aggbuf, b1, x1, NN * D / 4);

    // layer 2
    k_gemm<<<nBlkG, nThreads, 0, stream>>>(x1, W2, deg, hbuf, aggbuf, NN);
    k_edge_agg<<<nBlkAgg, nThreads, 0, stream>>>(src, dst, norm, hbuf, aggbuf, NE);

    // interleaved output [N, D, 2]
    k_finalize<<<nBlkF, nThreads, 0, stream>>>(x1, aggbuf, b2, out, NN * D);
}

// Round 2
// 597.348 us; speedup vs baseline: 4.9421x; 4.9421x over previous
//
#include <hip/hip_runtime.h>

#define NN 50000
#define NE 800000
#define D 128

// ---------------- init: deg = 1 (self-loop), cnt = 0 ----------------

__global__ __launch_bounds__(256) void k_init(float* __restrict__ deg,
                                              int* __restrict__ cnt, int n) {
    int i = blockIdx.x * 256 + threadIdx.x;
    if (i < n) { deg[i] = 1.0f; cnt[i] = 0; }
}

// ---------------- histogram: weighted degree + in-degree count ----------------

__global__ __launch_bounds__(256) void k_deg_cnt(const int* __restrict__ dst,
                                                 const float* __restrict__ ew,
                                                 float* __restrict__ deg,
                                                 int* __restrict__ cnt, int e) {
    int i = blockIdx.x * 256 + threadIdx.x;
    if (i < e) {
        int d = dst[i];
        atomicAdd(&deg[d], ew[i]);
        atomicAdd(&cnt[d], 1);
    }
}

// ---------------- exclusive scan of cnt -> rowptr, wofs (single block) ----------------

__global__ __launch_bounds__(1024) void k_scan(const int* __restrict__ cnt,
                                               int* __restrict__ rowptr,
                                               int* __restrict__ wofs, int n, int e) {
    __shared__ int sums[1024];
    const int tid = threadIdx.x;
    const int CH = (n + 1023) / 1024;
    const int base = tid * CH;

    int local = 0;
    for (int i = 0; i < CH; ++i) {
        int idx = base + i;
        if (idx < n) local += cnt[idx];
    }
    sums[tid] = local;
    __syncthreads();
    // Hillis-Steele inclusive scan
    for (int off = 1; off < 1024; off <<= 1) {
        int v = sums[tid];
        int add = (tid >= off) ? sums[tid - off] : 0;
        __syncthreads();
        sums[tid] = v + add;
        __syncthreads();
    }
    int run = (tid == 0) ? 0 : sums[tid - 1];
    for (int i = 0; i < CH; ++i) {
        int idx = base + i;
        if (idx < n) {
            rowptr[idx] = run;
            wofs[idx] = run;
            run += cnt[idx];
        }
    }
    if (tid == 0) rowptr[n] = e;
}

// ---------------- scatter edges into CSR, fused norm computation ----------------

__global__ __launch_bounds__(256) void k_scatter(const int* __restrict__ src,
                                                 const int* __restrict__ dst,
                                                 const float* __restrict__ ew,
                                                 const float* __restrict__ deg,
                                                 int* __restrict__ wofs,
                                                 int* __restrict__ col,
                                                 float* __restrict__ val, int e) {
    int i = blockIdx.x * 256 + threadIdx.x;
    if (i >= e) return;
    int s = src[i];
    int d = dst[i];
    float nrm = rsqrtf(deg[s]) * ew[i] * rsqrtf(deg[d]);
    int pos = atomicAdd(&wofs[d], 1);
    col[pos] = s;
    val[pos] = nrm;
}

// ---------------- GEMM: h = A @ W ----------------
// 256 threads, 32 nodes/block; x-tile in LDS; thread (g,c) owns 16 rows of col c.

__global__ __launch_bounds__(256) void k_gemm(const float* __restrict__ A,
                                              const float* __restrict__ W,
                                              float* __restrict__ h, int n) {
    __shared__ float xs[32][D];
    const int n0 = blockIdx.x * 32;
    const int tid = threadIdx.x;

#pragma unroll
    for (int i = 0; i < 16; ++i) {
        int idx = tid + i * 256;
        int r = idx >> 7, c = idx & 127;
        int nn = n0 + r;
        xs[r][c] = (nn < n) ? A[nn * D + c] : 0.0f;
    }
    __syncthreads();

    const int c = tid & 127;
    const int g = tid >> 7;

    float acc[16];
#pragma unroll
    for (int i = 0; i < 16; ++i) acc[i] = 0.0f;

    for (int k = 0; k < D; k += 4) {
        float w0 = W[(k + 0) * D + c];
        float w1 = W[(k + 1) * D + c];
        float w2 = W[(k + 2) * D + c];
        float w3 = W[(k + 3) * D + c];
#pragma unroll
        for (int i = 0; i < 16; ++i) {
            float4 xv = *(const float4*)&xs[g * 16 + i][k];
            acc[i] += xv.x * w0 + xv.y * w1 + xv.z * w2 + xv.w * w3;
        }
    }

#pragma unroll
    for (int i = 0; i < 16; ++i) {
        int nn = n0 + g * 16 + i;
        if (nn < n) h[nn * D + c] = acc[i];
    }
}

// ---------------- layer-1 aggregation: x1 = relu(Ahat h + b1) ----------------
// One wave per node; lane owns features [2*lane, 2*lane+1].

__global__ __launch_bounds__(256) void k_agg1(const int* __restrict__ rowptr,
                                              const int* __restrict__ col,
                                              const float* __restrict__ val,
                                              const float* __restrict__ deg,
                                              const float* __restrict__ h,
                                              const float* __restrict__ b,
                                              float* __restrict__ x1, int n) {
    int v = (blockIdx.x * 256 + threadIdx.x) >> 6;
    if (v >= n) return;
    int f = (threadIdx.x & 63) * 2;

    float dinv2 = 1.0f / deg[v];
    float2 hv = *(const float2*)&h[v * D + f];
    float accx = dinv2 * hv.x, accy = dinv2 * hv.y;

    int beg = rowptr[v], end = rowptr[v + 1];
    for (int i = beg; i < end; ++i) {
        int s = col[i];
        float w = val[i];
        float2 g = *(const float2*)&h[s * D + f];
        accx += w * g.x;
        accy += w * g.y;
    }
    float2 o;
    o.x = fmaxf(accx + b[f + 0], 0.0f);
    o.y = fmaxf(accy + b[f + 1], 0.0f);
    *(float2*)&x1[v * D + f] = o;
}

// ---------------- layer-2 aggregation + interleaved output ----------------
// out[v][f][0] = x1[v][f], out[v][f][1] = relu((Ahat h2 + b2)[v][f])

__global__ __launch_bounds__(256) void k_agg2(const int* __restrict__ rowptr,
                                              const int* __restrict__ col,
                                              const float* __restrict__ val,
                                              const float* __restrict__ deg,
                                              const float* __restrict__ h,
                                              const float* __restrict__ x1,
                                              const float* __restrict__ b,
                                              float* __restrict__ out, int n) {
    int v = (blockIdx.x * 256 + threadIdx.x) >> 6;
    if (v >= n) return;
    int f = (threadIdx.x & 63) * 2;

    float dinv2 = 1.0f / deg[v];
    float2 hv = *(const float2*)&h[v * D + f];
    float accx = dinv2 * hv.x, accy = dinv2 * hv.y;

    int beg = rowptr[v], end = rowptr[v + 1];
    for (int i = beg; i < end; ++i) {
        int s = col[i];
        float w = val[i];
        float2 g = *(const float2*)&h[s * D + f];
        accx += w * g.x;
        accy += w * g.y;
    }
    float2 xv = *(const float2*)&x1[v * D + f];
    float4 o;
    o.x = xv.x;
    o.y = fmaxf(accx + b[f + 0], 0.0f);
    o.z = xv.y;
    o.w = fmaxf(accy + b[f + 1], 0.0f);
    *(float4*)&out[(v * D + f) * 2] = o;
}

extern "C" void kernel_launch(void* const* d_in, const int* in_sizes, int n_in,
                              void* d_out, int out_size, void* d_ws, size_t ws_size,
                              hipStream_t stream) {
    const float* x  = (const float*)d_in[0];
    const int*   ei = (const int*)d_in[1];
    const float* ew = (const float*)d_in[2];
    const float* W1 = (const float*)d_in[3];
    const float* b1 = (const float*)d_in[4];
    const float* W2 = (const float*)d_in[5];
    const float* b2 = (const float*)d_in[6];
    float* out = (float*)d_out;

    const int* src = ei;
    const int* dst = ei + NE;

    char* w = (char*)d_ws;
    auto take = [&](size_t bytes) {
        char* p = w;
        w += (bytes + 255) & ~(size_t)255;
        return p;
    };
    float* deg    = (float*)take((size_t)NN * 4);
    int*   cnt    = (int*)take((size_t)NN * 4);
    int*   rowptr = (int*)take((size_t)(NN + 1) * 4);
    int*   wofs   = (int*)take((size_t)NN * 4);
    int*   col    = (int*)take((size_t)NE * 4);
    float* val    = (float*)take((size_t)NE * 4);
    float* hbuf   = (float*)take((size_t)NN * D * 4);
    float* x1     = (float*)take((size_t)NN * D * 4);

    const int nBlkN   = (NN + 255) / 256;
    const int nBlkE   = (NE + 255) / 256;
    const int nBlkG   = (NN + 31) / 32;
    const int nBlkAgg = (NN * 64 + 255) / 256;  // one wave per node

    // CSR build (per-call; ws is re-poisoned every launch)
    k_init<<<nBlkN, 256, 0, stream>>>(deg, cnt, NN);
    k_deg_cnt<<<nBlkE, 256, 0, stream>>>(dst, ew, deg, cnt, NE);
    k_scan<<<1, 1024, 0, stream>>>(cnt, rowptr, wofs, NN, NE);
    k_scatter<<<nBlkE, 256, 0, stream>>>(src, dst, ew, deg, wofs, col, val, NE);

    // layer 1
    k_gemm<<<nBlkG, 256, 0, stream>>>(x, W1, hbuf, NN);
    k_agg1<<<nBlkAgg, 256, 0, stream>>>(rowptr, col, val, deg, hbuf, b1, x1, NN);

    // layer 2
    k_gemm<<<nBlkG, 256, 0, stream>>>(x1, W2, hbuf, NN);
    k_agg2<<<nBlkAgg, 256, 0, stream>>>(rowptr, col, val, deg, hbuf, x1, b2, out, NN);
}

// Round 3
// 487.874 us; speedup vs baseline: 6.0510x; 1.2244x over previous
//
#include <hip/hip_runtime.h>

#define NN 50000
#define NE 800000
#define D 128
#define SCAN_CH 1024                      // elements per scan block
#define SCAN_NB ((NN + SCAN_CH - 1) / SCAN_CH)  // 49

// ---------------- init: deg = 1 (self-loop), cnt = 0 ----------------

__global__ __launch_bounds__(256) void k_init(float* __restrict__ deg,
                                              int* __restrict__ cnt, int n) {
    int i = blockIdx.x * 256 + threadIdx.x;
    if (i < n) { deg[i] = 1.0f; cnt[i] = 0; }
}

// ---------------- histogram: weighted degree + in-degree count ----------------

__global__ __launch_bounds__(256) void k_deg_cnt(const int* __restrict__ dst,
                                                 const float* __restrict__ ew,
                                                 float* __restrict__ deg,
                                                 int* __restrict__ cnt, int e) {
    int i = blockIdx.x * 256 + threadIdx.x;
    if (i < e) {
        int d = dst[i];
        atomicAdd(&deg[d], ew[i]);
        atomicAdd(&cnt[d], 1);
    }
}

// ---------------- hierarchical scan ----------------
// pass 1: per-block totals (each block covers 1024 elements, 4/thread)

__global__ __launch_bounds__(256) void k_scan_part(const int* __restrict__ cnt,
                                                   int* __restrict__ blockSums, int n) {
    __shared__ int s[256];
    const int tid = threadIdx.x;
    const int base = blockIdx.x * SCAN_CH + tid * 4;

    int c0 = 0, c1 = 0, c2 = 0, c3 = 0;
    if (base + 3 < n) {
        int4 v = *(const int4*)&cnt[base];
        c0 = v.x; c1 = v.y; c2 = v.z; c3 = v.w;
    } else {
        if (base + 0 < n) c0 = cnt[base + 0];
        if (base + 1 < n) c1 = cnt[base + 1];
        if (base + 2 < n) c2 = cnt[base + 2];
        if (base + 3 < n) c3 = cnt[base + 3];
    }
    s[tid] = c0 + c1 + c2 + c3;
    __syncthreads();
    for (int off = 1; off < 256; off <<= 1) {
        int v = s[tid];
        int add = (tid >= off) ? s[tid - off] : 0;
        __syncthreads();
        s[tid] = v + add;
        __syncthreads();
    }
    if (tid == 255) blockSums[blockIdx.x] = s[255];
}

// pass 2: exclusive scan of block sums (one wave, shfl)

__global__ __launch_bounds__(64) void k_scan_mid(const int* __restrict__ blockSums,
                                                 int* __restrict__ blockOffs, int nb) {
    int l = threadIdx.x;
    int v = (l < nb) ? blockSums[l] : 0;
    int inc = v;
#pragma unroll
    for (int off = 1; off < 64; off <<= 1) {
        int u = __shfl_up(inc, off);
        if (l >= off) inc += u;
    }
    if (l < nb) blockOffs[l] = inc - v;  // exclusive
}

// pass 3: local exclusive scan + block offset -> rowptr, wofs

__global__ __launch_bounds__(256) void k_scan_add(const int* __restrict__ cnt,
                                                  const int* __restrict__ blockOffs,
                                                  int* __restrict__ rowptr,
                                                  int* __restrict__ wofs, int n, int e) {
    __shared__ int s[256];
    const int tid = threadIdx.x;
    const int base = blockIdx.x * SCAN_CH + tid * 4;

    int c0 = 0, c1 = 0, c2 = 0, c3 = 0;
    if (base + 3 < n) {
        int4 v = *(const int4*)&cnt[base];
        c0 = v.x; c1 = v.y; c2 = v.z; c3 = v.w;
    } else {
        if (base + 0 < n) c0 = cnt[base + 0];
        if (base + 1 < n) c1 = cnt[base + 1];
        if (base + 2 < n) c2 = cnt[base + 2];
        if (base + 3 < n) c3 = cnt[base + 3];
    }
    int tsum = c0 + c1 + c2 + c3;
    s[tid] = tsum;
    __syncthreads();
    for (int off = 1; off < 256; off <<= 1) {
        int v = s[tid];
        int add = (tid >= off) ? s[tid - off] : 0;
        __syncthreads();
        s[tid] = v + add;
        __syncthreads();
    }
    int texcl = s[tid] - tsum;  // exclusive prefix of this thread within block
    int p = blockOffs[blockIdx.x] + texcl;

    int p0 = p, p1 = p + c0, p2 = p + c0 + c1, p3 = p + c0 + c1 + c2;
    if (base + 3 < n) {
        *(int4*)&rowptr[base] = make_int4(p0, p1, p2, p3);
        *(int4*)&wofs[base]   = make_int4(p0, p1, p2, p3);
    } else {
        if (base + 0 < n) { rowptr[base + 0] = p0; wofs[base + 0] = p0; }
        if (base + 1 < n) { rowptr[base + 1] = p1; wofs[base + 1] = p1; }
        if (base + 2 < n) { rowptr[base + 2] = p2; wofs[base + 2] = p2; }
    }
    if (blockIdx.x == 0 && tid == 0) rowptr[n] = e;
}

// ---------------- scatter edges into CSR, fused norm computation ----------------

__global__ __launch_bounds__(256) void k_scatter(const int* __restrict__ src,
                                                 const int* __restrict__ dst,
                                                 const float* __restrict__ ew,
                                                 const float* __restrict__ deg,
                                                 int* __restrict__ wofs,
                                                 int* __restrict__ col,
                                                 float* __restrict__ val, int e) {
    int i = blockIdx.x * 256 + threadIdx.x;
    if (i >= e) return;
    int s = src[i];
    int d = dst[i];
    float nrm = rsqrtf(deg[s]) * ew[i] * rsqrtf(deg[d]);
    int pos = atomicAdd(&wofs[d], 1);
    col[pos] = s;
    val[pos] = nrm;
}

// ---------------- GEMM: h = A @ W ----------------

__global__ __launch_bounds__(256) void k_gemm(const float* __restrict__ A,
                                              const float* __restrict__ W,
                                              float* __restrict__ h, int n) {
    __shared__ float xs[32][D];
    const int n0 = blockIdx.x * 32;
    const int tid = threadIdx.x;

#pragma unroll
    for (int i = 0; i < 16; ++i) {
        int idx = tid + i * 256;
        int r = idx >> 7, c = idx & 127;
        int nn = n0 + r;
        xs[r][c] = (nn < n) ? A[nn * D + c] : 0.0f;
    }
    __syncthreads();

    const int c = tid & 127;
    const int g = tid >> 7;

    float acc[16];
#pragma unroll
    for (int i = 0; i < 16; ++i) acc[i] = 0.0f;

    for (int k = 0; k < D; k += 4) {
        float w0 = W[(k + 0) * D + c];
        float w1 = W[(k + 1) * D + c];
        float w2 = W[(k + 2) * D + c];
        float w3 = W[(k + 3) * D + c];
#pragma unroll
        for (int i = 0; i < 16; ++i) {
            float4 xv = *(const float4*)&xs[g * 16 + i][k];
            acc[i] += xv.x * w0 + xv.y * w1 + xv.z * w2 + xv.w * w3;
        }
    }

#pragma unroll
    for (int i = 0; i < 16; ++i) {
        int nn = n0 + g * 16 + i;
        if (nn < n) h[nn * D + c] = acc[i];
    }
}

// ---------------- layer-1 aggregation: x1 = relu(Ahat h + b1) ----------------

__global__ __launch_bounds__(256) void k_agg1(const int* __restrict__ rowptr,
                                              const int* __restrict__ col,
                                              const float* __restrict__ val,
                                              const float* __restrict__ deg,
                                              const float* __restrict__ h,
                                              const float* __restrict__ b,
                                              float* __restrict__ x1, int n) {
    int v = (blockIdx.x * 256 + threadIdx.x) >> 6;
    if (v >= n) return;
    int f = (threadIdx.x & 63) * 2;

    float dinv2 = 1.0f / deg[v];
    float2 hv = *(const float2*)&h[v * D + f];
    float accx = dinv2 * hv.x, accy = dinv2 * hv.y;

    int beg = rowptr[v], end = rowptr[v + 1];
    for (int i = beg; i < end; ++i) {
        int s = col[i];
        float w = val[i];
        float2 g = *(const float2*)&h[s * D + f];
        accx += w * g.x;
        accy += w * g.y;
    }
    float2 o;
    o.x = fmaxf(accx + b[f + 0], 0.0f);
    o.y = fmaxf(accy + b[f + 1], 0.0f);
    *(float2*)&x1[v * D + f] = o;
}

// ---------------- layer-2 aggregation + interleaved output ----------------

__global__ __launch_bounds__(256) void k_agg2(const int* __restrict__ rowptr,
                                              const int* __restrict__ col,
                                              const float* __restrict__ val,
                                              const float* __restrict__ deg,
                                              const float* __restrict__ h,
                                              const float* __restrict__ x1,
                                              const float* __restrict__ b,
                                              float* __restrict__ out, int n) {
    int v = (blockIdx.x * 256 + threadIdx.x) >> 6;
    if (v >= n) return;
    int f = (threadIdx.x & 63) * 2;

    float dinv2 = 1.0f / deg[v];
    float2 hv = *(const float2*)&h[v * D + f];
    float accx = dinv2 * hv.x, accy = dinv2 * hv.y;

    int beg = rowptr[v], end = rowptr[v + 1];
    for (int i = beg; i < end; ++i) {
        int s = col[i];
        float w = val[i];
        float2 g = *(const float2*)&h[s * D + f];
        accx += w * g.x;
        accy += w * g.y;
    }
    float2 xv = *(const float2*)&x1[v * D + f];
    float4 o;
    o.x = xv.x;
    o.y = fmaxf(accx + b[f + 0], 0.0f);
    o.z = xv.y;
    o.w = fmaxf(accy + b[f + 1], 0.0f);
    *(float4*)&out[(v * D + f) * 2] = o;
}

extern "C" void kernel_launch(void* const* d_in, const int* in_sizes, int n_in,
                              void* d_out, int out_size, void* d_ws, size_t ws_size,
                              hipStream_t stream) {
    const float* x  = (const float*)d_in[0];
    const int*   ei = (const int*)d_in[1];
    const float* ew = (const float*)d_in[2];
    const float* W1 = (const float*)d_in[3];
    const float* b1 = (const float*)d_in[4];
    const float* W2 = (const float*)d_in[5];
    const float* b2 = (const float*)d_in[6];
    float* out = (float*)d_out;

    const int* src = ei;
    const int* dst = ei + NE;

    char* w = (char*)d_ws;
    auto take = [&](size_t bytes) {
        char* p = w;
        w += (bytes + 255) & ~(size_t)255;
        return p;
    };
    float* deg       = (float*)take((size_t)NN * 4);
    int*   cnt       = (int*)take((size_t)NN * 4);
    int*   rowptr    = (int*)take((size_t)(NN + 1) * 4);
    int*   wofs      = (int*)take((size_t)NN * 4);
    int*   blockSums = (int*)take((size_t)SCAN_NB * 4);
    int*   blockOffs = (int*)take((size_t)SCAN_NB * 4);
    int*   col       = (int*)take((size_t)NE * 4);
    float* val       = (float*)take((size_t)NE * 4);
    float* hbuf      = (float*)take((size_t)NN * D * 4);
    float* x1        = (float*)take((size_t)NN * D * 4);

    const int nBlkN   = (NN + 255) / 256;
    const int nBlkE   = (NE + 255) / 256;
    const int nBlkG   = (NN + 31) / 32;
    const int nBlkAgg = (NN * 64 + 255) / 256;  // one wave per node

    // CSR build
    k_init<<<nBlkN, 256, 0, stream>>>(deg, cnt, NN);
    k_deg_cnt<<<nBlkE, 256, 0, stream>>>(dst, ew, deg, cnt, NE);
    k_scan_part<<<SCAN_NB, 256, 0, stream>>>(cnt, blockSums, NN);
    k_scan_mid<<<1, 64, 0, stream>>>(blockSums, blockOffs, SCAN_NB);
    k_scan_add<<<SCAN_NB, 256, 0, stream>>>(cnt, blockOffs, rowptr, wofs, NN, NE);
    k_scatter<<<nBlkE, 256, 0, stream>>>(src, dst, ew, deg, wofs, col, val, NE);

    // layer 1
    k_gemm<<<nBlkG, 256, 0, stream>>>(x, W1, hbuf, NN);
    k_agg1<<<nBlkAgg, 256, 0, stream>>>(rowptr, col, val, deg, hbuf, b1, x1, NN);

    // layer 2
    k_gemm<<<nBlkG, 256, 0, stream>>>(x1, W2, hbuf, NN);
    k_agg2<<<nBlkAgg, 256, 0, stream>>>(rowptr, col, val, deg, hbuf, x1, b2, out, NN);
}

// Round 5
// 354.900 us; speedup vs baseline: 8.3182x; 1.3747x over previous
//
#include <hip/hip_runtime.h>

#define NN 50000
#define NE 800000
#define D 128
#define SCAN_CH 1024
#define SCAN_NB ((NN + SCAN_CH - 1) / SCAN_CH)  // 49

typedef __attribute__((ext_vector_type(8))) short short8;
typedef __attribute__((ext_vector_type(4))) float f32x4;
typedef unsigned short ushort;
typedef unsigned int uint;

__device__ inline ushort f2b(float x) {  // f32 -> bf16 RNE
    uint u = __float_as_uint(x);
    return (ushort)((u + 0x7fffu + ((u >> 16) & 1u)) >> 16);
}
__device__ inline float blo(uint u) { return __uint_as_float(u << 16); }
__device__ inline float bhi(uint u) { return __uint_as_float(u & 0xffff0000u); }

// ---------------- init ----------------

__global__ __launch_bounds__(256) void k_init(float* __restrict__ deg,
                                              int* __restrict__ cnt, int n) {
    int i = blockIdx.x * 256 + threadIdx.x;
    if (i < n) { deg[i] = 1.0f; cnt[i] = 0; }
}

// ---------------- W transpose + bf16 convert: wtb[c][k] = W[k][c] ----------------

__global__ __launch_bounds__(256) void k_wt(const float* __restrict__ W1,
                                            const float* __restrict__ W2,
                                            ushort* __restrict__ wtb1,
                                            ushort* __restrict__ wtb2) {
    int g = blockIdx.x * 256 + threadIdx.x;
    const float* W = (g < D * D) ? W1 : W2;
    ushort* wt = (g < D * D) ? wtb1 : wtb2;
    int idx = (g < D * D) ? g : g - D * D;
    if (g < 2 * D * D) {
        int k = idx >> 7, c = idx & 127;
        wt[c * D + k] = f2b(W[idx]);
    }
}

// ---------------- histogram: weighted degree + count + per-edge rank ----------------

__global__ __launch_bounds__(256) void k_deg_cnt(const int* __restrict__ dst,
                                                 const float* __restrict__ ew,
                                                 float* __restrict__ deg,
                                                 int* __restrict__ cnt,
                                                 int* __restrict__ erank, int e) {
    int i = blockIdx.x * 256 + threadIdx.x;
    if (i < e) {
        int d = dst[i];
        atomicAdd(&deg[d], ew[i]);
        erank[i] = atomicAdd(&cnt[d], 1);
    }
}

// ---------------- hierarchical scan ----------------

__global__ __launch_bounds__(256) void k_scan_part(const int* __restrict__ cnt,
                                                   int* __restrict__ blockSums, int n) {
    __shared__ int s[256];
    const int tid = threadIdx.x;
    const int base = blockIdx.x * SCAN_CH + tid * 4;
    int c0 = 0, c1 = 0, c2 = 0, c3 = 0;
    if (base + 3 < n) {
        int4 v = *(const int4*)&cnt[base];
        c0 = v.x; c1 = v.y; c2 = v.z; c3 = v.w;
    } else {
        if (base + 0 < n) c0 = cnt[base + 0];
        if (base + 1 < n) c1 = cnt[base + 1];
        if (base + 2 < n) c2 = cnt[base + 2];
    }
    s[tid] = c0 + c1 + c2 + c3;
    __syncthreads();
    for (int off = 1; off < 256; off <<= 1) {
        int v = s[tid];
        int add = (tid >= off) ? s[tid - off] : 0;
        __syncthreads();
        s[tid] = v + add;
        __syncthreads();
    }
    if (tid == 255) blockSums[blockIdx.x] = s[255];
}

__global__ __launch_bounds__(64) void k_scan_mid(const int* __restrict__ blockSums,
                                                 int* __restrict__ blockOffs, int nb) {
    int l = threadIdx.x;
    int v = (l < nb) ? blockSums[l] : 0;
    int inc = v;
#pragma unroll
    for (int off = 1; off < 64; off <<= 1) {
        int u = __shfl_up(inc, off);
        if (l >= off) inc += u;
    }
    if (l < nb) blockOffs[l] = inc - v;
}

__global__ __launch_bounds__(256) void k_scan_add(const int* __restrict__ cnt,
                                                  const int* __restrict__ blockOffs,
                                                  int* __restrict__ rowptr, int n, int e) {
    __shared__ int s[256];
    const int tid = threadIdx.x;
    const int base = blockIdx.x * SCAN_CH + tid * 4;
    int c0 = 0, c1 = 0, c2 = 0, c3 = 0;
    if (base + 3 < n) {
        int4 v = *(const int4*)&cnt[base];
        c0 = v.x; c1 = v.y; c2 = v.z; c3 = v.w;
    } else {
        if (base + 0 < n) c0 = cnt[base + 0];
        if (base + 1 < n) c1 = cnt[base + 1];
        if (base + 2 < n) c2 = cnt[base + 2];
    }
    int tsum = c0 + c1 + c2 + c3;
    s[tid] = tsum;
    __syncthreads();
    for (int off = 1; off < 256; off <<= 1) {
        int v = s[tid];
        int add = (tid >= off) ? s[tid - off] : 0;
        __syncthreads();
        s[tid] = v + add;
        __syncthreads();
    }
    int p = blockOffs[blockIdx.x] + s[tid] - tsum;
    int p0 = p, p1 = p + c0, p2 = p + c0 + c1, p3 = p + c0 + c1 + c2;
    if (base + 3 < n) {
        *(int4*)&rowptr[base] = make_int4(p0, p1, p2, p3);
    } else {
        if (base + 0 < n) rowptr[base + 0] = p0;
        if (base + 1 < n) rowptr[base + 1] = p1;
        if (base + 2 < n) rowptr[base + 2] = p2;
    }
    if (blockIdx.x == 0 && tid == 0) rowptr[n] = e;
}

// ---------------- scatter (atomic-free): CSR fill + fused norm ----------------

__global__ __launch_bounds__(256) void k_scatter(const int* __restrict__ src,
                                                 const int* __restrict__ dst,
                                                 const float* __restrict__ ew,
                                                 const float* __restrict__ deg,
                                                 const int* __restrict__ rowptr,
                                                 const int* __restrict__ erank,
                                                 int* __restrict__ col,
                                                 float* __restrict__ val, int e) {
    int i = blockIdx.x * 256 + threadIdx.x;
    if (i >= e) return;
    int s = src[i];
    int d = dst[i];
    float nrm = rsqrtf(deg[s]) * ew[i] * rsqrtf(deg[d]);
    int pos = rowptr[d] + erank[i];
    col[pos] = s;
    val[pos] = nrm;
}

// ---------------- MFMA GEMM: h(bf16) = A(f32) @ W via wtb(bf16, [c][k]) ----------------
// 256 thr = 4 waves; wave w owns 16 nodes. A-frags direct from global (f32->bf16),
// B-frags direct from wtb (L2-resident). C through LDS bounce for coalesced stores.
// k-mapping pi(h,j)=h*8+j used consistently for A and B (sum over k is order-free).

__global__ __launch_bounds__(256) void k_gemm(const float* __restrict__ A,
                                              const ushort* __restrict__ wtb,
                                              ushort* __restrict__ h, int n) {
    __shared__ ushort bounce[4][16][136];  // stride 136 ushorts = 272 B (16B-aligned rows)
    const int w = threadIdx.x >> 6, l = threadIdx.x & 63;
    const int r = l & 15, hg = l >> 4;
    const int node = blockIdx.x * 64 + w * 16 + r;
    const bool valid = node < n;
    const float* arow = A + (size_t)(valid ? node : 0) * D;

    short8 afr[4];
#pragma unroll
    for (int kk = 0; kk < 4; ++kk) {
        float4 p = *(const float4*)(arow + kk * 32 + hg * 8);
        float4 q = *(const float4*)(arow + kk * 32 + hg * 8 + 4);
        short8 t;
        t[0] = (short)f2b(p.x); t[1] = (short)f2b(p.y);
        t[2] = (short)f2b(p.z); t[3] = (short)f2b(p.w);
        t[4] = (short)f2b(q.x); t[5] = (short)f2b(q.y);
        t[6] = (short)f2b(q.z); t[7] = (short)f2b(q.w);
        afr[kk] = t;
    }

#pragma unroll
    for (int ct = 0; ct < 8; ++ct) {
        f32x4 acc = {0.f, 0.f, 0.f, 0.f};
#pragma unroll
        for (int kk = 0; kk < 4; ++kk) {
            short8 b = *(const short8*)(wtb + (size_t)(ct * 16 + r) * D + kk * 32 + hg * 8);
            acc = __builtin_amdgcn_mfma_f32_16x16x32_bf16(afr[kk], b, acc, 0, 0, 0);
        }
#pragma unroll
        for (int g = 0; g < 4; ++g)
            bounce[w][hg * 4 + g][ct * 16 + r] = f2b(acc[g]);
    }
    __syncthreads();

    // store-out: wave tile = 16 nodes x 128 ch = 256 chunks of 8 ushorts (16 B).
    // 64 lanes x 4 iters, consecutive lanes -> consecutive chunks (coalesced 1 KB).
#pragma unroll
    for (int it = 0; it < 4; ++it) {
        int cid = it * 64 + l;   // 0..255
        int nl = cid >> 4;       // node 0..15
        int ch = cid & 15;       // 16-B chunk 0..15
        int onode = blockIdx.x * 64 + w * 16 + nl;
        if (onode < n) {
            int4 vv = *(const int4*)&bounce[w][nl][ch * 8];
            *(int4*)(h + (size_t)onode * D + ch * 8) = vv;
        }
    }
}

// ---------------- aggregation: one wave per node, shfl-broadcast edges ----------------
// lane owns features (2*lane, 2*lane+1); h gathered as bf16 (4 B/lane/edge).

__global__ __launch_bounds__(256) void k_agg1(const int* __restrict__ rowptr,
                                              const int* __restrict__ col,
                                              const float* __restrict__ val,
                                              const float* __restrict__ deg,
                                              const ushort* __restrict__ hb,
                                              const float* __restrict__ b,
                                              float* __restrict__ x1, int n) {
    int v = (blockIdx.x * 256 + threadIdx.x) >> 6;
    if (v >= n) return;
    int lane = threadIdx.x & 63;
    int f = lane * 2;

    float dinv2 = 1.0f / deg[v];
    uint us = *(const uint*)(hb + (size_t)v * D + f);
    float accx = dinv2 * blo(us);
    float accy = dinv2 * bhi(us);

    int beg = rowptr[v], end = rowptr[v + 1];
    for (int base = beg; base < end; base += 64) {
        int idx = base + lane;
        bool ok = idx < end;
        int cc = ok ? col[idx] : 0;
        float vv = ok ? val[idx] : 0.0f;
        int m = min(64, end - base);
        for (int i = 0; i < m; ++i) {
            int s = __shfl(cc, i);
            float ww = __shfl(vv, i);
            uint u = *(const uint*)(hb + (size_t)s * D + f);
            accx += ww * blo(u);
            accy += ww * bhi(u);
        }
    }
    float2 o;
    o.x = fmaxf(accx + b[f + 0], 0.0f);
    o.y = fmaxf(accy + b[f + 1], 0.0f);
    *(float2*)&x1[(size_t)v * D + f] = o;
}

__global__ __launch_bounds__(256) void k_agg2(const int* __restrict__ rowptr,
                                              const int* __restrict__ col,
                                              const float* __restrict__ val,
                                              const float* __restrict__ deg,
                                              const ushort* __restrict__ hb,
                                              const float* __restrict__ x1,
                                              const float* __restrict__ b,
                                              float* __restrict__ out, int n) {
    int v = (blockIdx.x * 256 + threadIdx.x) >> 6;
    if (v >= n) return;
    int lane = threadIdx.x & 63;
    int f = lane * 2;

    float dinv2 = 1.0f / deg[v];
    uint us = *(const uint*)(hb + (size_t)v * D + f);
    float accx = dinv2 * blo(us);
    float accy = dinv2 * bhi(us);

    int beg = rowptr[v], end = rowptr[v + 1];
    for (int base = beg; base < end; base += 64) {
        int idx = base + lane;
        bool ok = idx < end;
        int cc = ok ? col[idx] : 0;
        float vv = ok ? val[idx] : 0.0f;
        int m = min(64, end - base);
        for (int i = 0; i < m; ++i) {
            int s = __shfl(cc, i);
            float ww = __shfl(vv, i);
            uint u = *(const uint*)(hb + (size_t)s * D + f);
            accx += ww * blo(u);
            accy += ww * bhi(u);
        }
    }
    float2 xv = *(const float2*)&x1[(size_t)v * D + f];
    float4 o;
    o.x = xv.x;
    o.y = fmaxf(accx + b[f + 0], 0.0f);
    o.z = xv.y;
    o.w = fmaxf(accy + b[f + 1], 0.0f);
    *(float4*)&out[((size_t)v * D + f) * 2] = o;
}

extern "C" void kernel_launch(void* const* d_in, const int* in_sizes, int n_in,
                              void* d_out, int out_size, void* d_ws, size_t ws_size,
                              hipStream_t stream) {
    const float* x  = (const float*)d_in[0];
    const int*   ei = (const int*)d_in[1];
    const float* ew = (const float*)d_in[2];
    const float* W1 = (const float*)d_in[3];
    const float* b1 = (const float*)d_in[4];
    const float* W2 = (const float*)d_in[5];
    const float* b2 = (const float*)d_in[6];
    float* out = (float*)d_out;

    const int* src = ei;
    const int* dst = ei + NE;

    char* w = (char*)d_ws;
    auto take = [&](size_t bytes) {
        char* p = w;
        w += (bytes + 255) & ~(size_t)255;
        return p;
    };
    float*  deg       = (float*)take((size_t)NN * 4);
    int*    cnt       = (int*)take((size_t)NN * 4);
    int*    rowptr    = (int*)take((size_t)(NN + 1) * 4);
    int*    blockSums = (int*)take((size_t)SCAN_NB * 4);
    int*    blockOffs = (int*)take((size_t)SCAN_NB * 4);
    int*    erank     = (int*)take((size_t)NE * 4);
    int*    col       = (int*)take((size_t)NE * 4);
    float*  val       = (float*)take((size_t)NE * 4);
    ushort* wtb1      = (ushort*)take((size_t)D * D * 2);
    ushort* wtb2      = (ushort*)take((size_t)D * D * 2);
    ushort* hb        = (ushort*)take((size_t)NN * D * 2);
    float*  x1        = (float*)take((size_t)NN * D * 4);

    const int nBlkN   = (NN + 255) / 256;
    const int nBlkE   = (NE + 255) / 256;
    const int nBlkG   = (NN + 63) / 64;
    const int nBlkAgg = (NN * 64 + 255) / 256;
    const int nBlkW   = (2 * D * D + 255) / 256;

    // CSR build + weight transpose
    k_wt<<<nBlkW, 256, 0, stream>>>(W1, W2, wtb1, wtb2);
    k_init<<<nBlkN, 256, 0, stream>>>(deg, cnt, NN);
    k_deg_cnt<<<nBlkE, 256, 0, stream>>>(dst, ew, deg, cnt, erank, NE);
    k_scan_part<<<SCAN_NB, 256, 0, stream>>>(cnt, blockSums, NN);
    k_scan_mid<<<1, 64, 0, stream>>>(blockSums, blockOffs, SCAN_NB);
    k_scan_add<<<SCAN_NB, 256, 0, stream>>>(cnt, blockOffs, rowptr, NN, NE);
    k_scatter<<<nBlkE, 256, 0, stream>>>(src, dst, ew, deg, rowptr, erank, col, val, NE);

    // layer 1
    k_gemm<<<nBlkG, 256, 0, stream>>>(x, wtb1, hb, NN);
    k_agg1<<<nBlkAgg, 256, 0, stream>>>(rowptr, col, val, deg, hb, b1, x1, NN);

    // layer 2
    k_gemm<<<nBlkG, 256, 0, stream>>>(x1, wtb2, hb, NN);
    k_agg2<<<nBlkAgg, 256, 0, stream>>>(rowptr, col, val, deg, hb, x1, b2, out, NN);
}

// Round 6
// 306.530 us; speedup vs baseline: 9.6308x; 1.1578x over previous
//
#include <hip/hip_runtime.h>

#define NN 50000
#define NE 800000
#define D 128
#define SCAN_CH 1024
#define SCAN_NB ((NN + SCAN_CH - 1) / SCAN_CH)  // 49

typedef __attribute__((ext_vector_type(8))) short short8;
typedef __attribute__((ext_vector_type(4))) float f32x4;
typedef unsigned short ushort;
typedef unsigned int uint;
typedef unsigned long long u64;

__device__ inline ushort f2b(float x) {  // f32 -> bf16 RNE
    uint u = __float_as_uint(x);
    return (ushort)((u + 0x7fffu + ((u >> 16) & 1u)) >> 16);
}
__device__ inline float blo(uint u) { return __uint_as_float(u << 16); }
__device__ inline float bhi(uint u) { return __uint_as_float(u & 0xffff0000u); }

// ---------------- init: packed (cnt<<32 | deg_fix24) = 0 ----------------

__global__ __launch_bounds__(256) void k_init(u64* __restrict__ pc, int n) {
    int i = blockIdx.x * 256 + threadIdx.x;
    if (i < n) pc[i] = 0ull;
}

// ---------------- W transpose + bf16 convert: wtb[c][k] = W[k][c] ----------------

__global__ __launch_bounds__(256) void k_wt(const float* __restrict__ W1,
                                            const float* __restrict__ W2,
                                            ushort* __restrict__ wtb1,
                                            ushort* __restrict__ wtb2) {
    int g = blockIdx.x * 256 + threadIdx.x;
    const float* W = (g < D * D) ? W1 : W2;
    ushort* wt = (g < D * D) ? wtb1 : wtb2;
    int idx = (g < D * D) ? g : g - D * D;
    if (g < 2 * D * D) {
        int k = idx >> 7, c = idx & 127;
        wt[c * D + k] = f2b(W[idx]);
    }
}

// ---------------- fused histogram: one 64-bit atomic per edge ----------------
// high 32: in-degree count; low 32: weighted degree in 8.24 fixed point.

__global__ __launch_bounds__(256) void k_deg_cnt(const int* __restrict__ dst,
                                                 const float* __restrict__ ew,
                                                 u64* __restrict__ pc,
                                                 int* __restrict__ erank, int e) {
    int i = blockIdx.x * 256 + threadIdx.x;
    if (i < e) {
        int d = dst[i];
        uint fx = (uint)(ew[i] * 16777216.0f + 0.5f);
        u64 pack = (1ull << 32) | (u64)fx;
        u64 old = atomicAdd(&pc[d], pack);
        erank[i] = (int)(old >> 32);
    }
}

// ---------------- hierarchical scan (counts from pc hi-words) ----------------
// pass 1 also materializes deg[] = 1 + fix24->float.

__global__ __launch_bounds__(256) void k_scan_part(const u64* __restrict__ pc,
                                                   int* __restrict__ blockSums,
                                                   float* __restrict__ deg, int n) {
    __shared__ int s[256];
    const int tid = threadIdx.x;
    const int base = blockIdx.x * SCAN_CH + tid * 4;
    int c0 = 0, c1 = 0, c2 = 0, c3 = 0;
    const float sc = 1.0f / 16777216.0f;
    if (base + 3 < n) {
        u64 p0 = pc[base + 0], p1 = pc[base + 1], p2 = pc[base + 2], p3 = pc[base + 3];
        c0 = (int)(p0 >> 32); c1 = (int)(p1 >> 32);
        c2 = (int)(p2 >> 32); c3 = (int)(p3 >> 32);
        float4 dv;
        dv.x = 1.0f + (float)(uint)p0 * sc;
        dv.y = 1.0f + (float)(uint)p1 * sc;
        dv.z = 1.0f + (float)(uint)p2 * sc;
        dv.w = 1.0f + (float)(uint)p3 * sc;
        *(float4*)&deg[base] = dv;
    } else {
        for (int j = 0; j < 4; ++j) {
            if (base + j < n) {
                u64 p = pc[base + j];
                int cj = (int)(p >> 32);
                if (j == 0) c0 = cj; else if (j == 1) c1 = cj; else if (j == 2) c2 = cj; else c3 = cj;
                deg[base + j] = 1.0f + (float)(uint)p * sc;
            }
        }
    }
    s[tid] = c0 + c1 + c2 + c3;
    __syncthreads();
    for (int off = 1; off < 256; off <<= 1) {
        int v = s[tid];
        int add = (tid >= off) ? s[tid - off] : 0;
        __syncthreads();
        s[tid] = v + add;
        __syncthreads();
    }
    if (tid == 255) blockSums[blockIdx.x] = s[255];
}

__global__ __launch_bounds__(64) void k_scan_mid(const int* __restrict__ blockSums,
                                                 int* __restrict__ blockOffs, int nb) {
    int l = threadIdx.x;
    int v = (l < nb) ? blockSums[l] : 0;
    int inc = v;
#pragma unroll
    for (int off = 1; off < 64; off <<= 1) {
        int u = __shfl_up(inc, off);
        if (l >= off) inc += u;
    }
    if (l < nb) blockOffs[l] = inc - v;
}

__global__ __launch_bounds__(256) void k_scan_add(const u64* __restrict__ pc,
                                                  const int* __restrict__ blockOffs,
                                                  int* __restrict__ rowptr, int n, int e) {
    __shared__ int s[256];
    const int tid = threadIdx.x;
    const int base = blockIdx.x * SCAN_CH + tid * 4;
    int c0 = 0, c1 = 0, c2 = 0, c3 = 0;
    if (base + 3 < n) {
        c0 = (int)(pc[base + 0] >> 32); c1 = (int)(pc[base + 1] >> 32);
        c2 = (int)(pc[base + 2] >> 32); c3 = (int)(pc[base + 3] >> 32);
    } else {
        if (base + 0 < n) c0 = (int)(pc[base + 0] >> 32);
        if (base + 1 < n) c1 = (int)(pc[base + 1] >> 32);
        if (base + 2 < n) c2 = (int)(pc[base + 2] >> 32);
    }
    int tsum = c0 + c1 + c2 + c3;
    s[tid] = tsum;
    __syncthreads();
    for (int off = 1; off < 256; off <<= 1) {
        int v = s[tid];
        int add = (tid >= off) ? s[tid - off] : 0;
        __syncthreads();
        s[tid] = v + add;
        __syncthreads();
    }
    int p = blockOffs[blockIdx.x] + s[tid] - tsum;
    int p0 = p, p1 = p + c0, p2 = p + c0 + c1, p3 = p + c0 + c1 + c2;
    if (base + 3 < n) {
        *(int4*)&rowptr[base] = make_int4(p0, p1, p2, p3);
    } else {
        if (base + 0 < n) rowptr[base + 0] = p0;
        if (base + 1 < n) rowptr[base + 1] = p1;
        if (base + 2 < n) rowptr[base + 2] = p2;
    }
    if (blockIdx.x == 0 && tid == 0) rowptr[n] = e;
}

// ---------------- scatter (atomic-free): packed {src, norm} per edge ----------------

__global__ __launch_bounds__(256) void k_scatter(const int* __restrict__ src,
                                                 const int* __restrict__ dst,
                                                 const float* __restrict__ ew,
                                                 const float* __restrict__ deg,
                                                 const int* __restrict__ rowptr,
                                                 const int* __restrict__ erank,
                                                 int2* __restrict__ edges, int e) {
    int i = blockIdx.x * 256 + threadIdx.x;
    if (i >= e) return;
    int s = src[i];
    int d = dst[i];
    float nrm = rsqrtf(deg[s]) * ew[i] * rsqrtf(deg[d]);
    int pos = rowptr[d] + erank[i];
    int2 ev;
    ev.x = s;
    ev.y = __float_as_int(nrm);
    edges[pos] = ev;
}

// ---------------- MFMA GEMM: h(bf16) = A(f32) @ W via wtb(bf16, [c][k]) ----------------

__global__ __launch_bounds__(256) void k_gemm(const float* __restrict__ A,
                                              const ushort* __restrict__ wtb,
                                              ushort* __restrict__ h, int n) {
    __shared__ ushort bounce[4][16][136];
    const int w = threadIdx.x >> 6, l = threadIdx.x & 63;
    const int r = l & 15, hg = l >> 4;
    const int node = blockIdx.x * 64 + w * 16 + r;
    const bool valid = node < n;
    const float* arow = A + (size_t)(valid ? node : 0) * D;

    short8 afr[4];
#pragma unroll
    for (int kk = 0; kk < 4; ++kk) {
        float4 p = *(const float4*)(arow + kk * 32 + hg * 8);
        float4 q = *(const float4*)(arow + kk * 32 + hg * 8 + 4);
        short8 t;
        t[0] = (short)f2b(p.x); t[1] = (short)f2b(p.y);
        t[2] = (short)f2b(p.z); t[3] = (short)f2b(p.w);
        t[4] = (short)f2b(q.x); t[5] = (short)f2b(q.y);
        t[6] = (short)f2b(q.z); t[7] = (short)f2b(q.w);
        afr[kk] = t;
    }

#pragma unroll
    for (int ct = 0; ct < 8; ++ct) {
        f32x4 acc = {0.f, 0.f, 0.f, 0.f};
#pragma unroll
        for (int kk = 0; kk < 4; ++kk) {
            short8 b = *(const short8*)(wtb + (size_t)(ct * 16 + r) * D + kk * 32 + hg * 8);
            acc = __builtin_amdgcn_mfma_f32_16x16x32_bf16(afr[kk], b, acc, 0, 0, 0);
        }
#pragma unroll
        for (int g = 0; g < 4; ++g)
            bounce[w][hg * 4 + g][ct * 16 + r] = f2b(acc[g]);
    }
    __syncthreads();

#pragma unroll
    for (int it = 0; it < 4; ++it) {
        int cid = it * 64 + l;
        int nl = cid >> 4;
        int ch = cid & 15;
        int onode = blockIdx.x * 64 + w * 16 + nl;
        if (onode < n) {
            int4 vv = *(const int4*)&bounce[w][nl][ch * 8];
            *(int4*)(h + (size_t)onode * D + ch * 8) = vv;
        }
    }
}

// ---------------- aggregation: one wave per node, readlane-broadcast edges ----------------

__global__ __launch_bounds__(256) void k_agg1(const int* __restrict__ rowptr,
                                              const int2* __restrict__ edges,
                                              const float* __restrict__ deg,
                                              const ushort* __restrict__ hb,
                                              const float* __restrict__ b,
                                              float* __restrict__ x1, int n) {
    int v = (blockIdx.x * 256 + threadIdx.x) >> 6;
    if (v >= n) return;
    int lane = threadIdx.x & 63;
    int f = lane * 2;

    float dinv2 = 1.0f / deg[v];
    uint us = *(const uint*)(hb + (size_t)v * D + f);
    float accx = dinv2 * blo(us);
    float accy = dinv2 * bhi(us);

    int beg = rowptr[v], end = rowptr[v + 1];
    for (int base = beg; base < end; base += 64) {
        int idx = base + lane;
        int2 ev = (idx < end) ? edges[idx] : make_int2(0, 0);
        int m = min(64, end - base);
#pragma unroll 4
        for (int i = 0; i < m; ++i) {
            int s = __builtin_amdgcn_readlane(ev.x, i);
            float ww = __uint_as_float((uint)__builtin_amdgcn_readlane(ev.y, i));
            uint u = *(const uint*)(hb + (size_t)s * D + f);
            accx += ww * blo(u);
            accy += ww * bhi(u);
        }
    }
    float2 o;
    o.x = fmaxf(accx + b[f + 0], 0.0f);
    o.y = fmaxf(accy + b[f + 1], 0.0f);
    *(float2*)&x1[(size_t)v * D + f] = o;
}

__global__ __launch_bounds__(256) void k_agg2(const int* __restrict__ rowptr,
                                              const int2* __restrict__ edges,
                                              const float* __restrict__ deg,
                                              const ushort* __restrict__ hb,
                                              const float* __restrict__ x1,
                                              const float* __restrict__ b,
                                              float* __restrict__ out, int n) {
    int v = (blockIdx.x * 256 + threadIdx.x) >> 6;
    if (v >= n) return;
    int lane = threadIdx.x & 63;
    int f = lane * 2;

    float dinv2 = 1.0f / deg[v];
    uint us = *(const uint*)(hb + (size_t)v * D + f);
    float accx = dinv2 * blo(us);
    float accy = dinv2 * bhi(us);

    int beg = rowptr[v], end = rowptr[v + 1];
    for (int base = beg; base < end; base += 64) {
        int idx = base + lane;
        int2 ev = (idx < end) ? edges[idx] : make_int2(0, 0);
        int m = min(64, end - base);
#pragma unroll 4
        for (int i = 0; i < m; ++i) {
            int s = __builtin_amdgcn_readlane(ev.x, i);
            float ww = __uint_as_float((uint)__builtin_amdgcn_readlane(ev.y, i));
            uint u = *(const uint*)(hb + (size_t)s * D + f);
            accx += ww * blo(u);
            accy += ww * bhi(u);
        }
    }
    float2 xv = *(const float2*)&x1[(size_t)v * D + f];
    float4 o;
    o.x = xv.x;
    o.y = fmaxf(accx + b[f + 0], 0.0f);
    o.z = xv.y;
    o.w = fmaxf(accy + b[f + 1], 0.0f);
    *(float4*)&out[((size_t)v * D + f) * 2] = o;
}

extern "C" void kernel_launch(void* const* d_in, const int* in_sizes, int n_in,
                              void* d_out, int out_size, void* d_ws, size_t ws_size,
                              hipStream_t stream) {
    const float* x  = (const float*)d_in[0];
    const int*   ei = (const int*)d_in[1];
    const float* ew = (const float*)d_in[2];
    const float* W1 = (const float*)d_in[3];
    const float* b1 = (const float*)d_in[4];
    const float* W2 = (const float*)d_in[5];
    const float* b2 = (const float*)d_in[6];
    float* out = (float*)d_out;

    const int* src = ei;
    const int* dst = ei + NE;

    char* w = (char*)d_ws;
    auto take = [&](size_t bytes) {
        char* p = w;
        w += (bytes + 255) & ~(size_t)255;
        return p;
    };
    u64*    pc        = (u64*)take((size_t)NN * 8);
    float*  deg       = (float*)take((size_t)NN * 4);
    int*    rowptr    = (int*)take((size_t)(NN + 1) * 4);
    int*    blockSums = (int*)take((size_t)SCAN_NB * 4);
    int*    blockOffs = (int*)take((size_t)SCAN_NB * 4);
    int*    erank     = (int*)take((size_t)NE * 4);
    int2*   edges     = (int2*)take((size_t)NE * 8);
    ushort* wtb1      = (ushort*)take((size_t)D * D * 2);
    ushort* wtb2      = (ushort*)take((size_t)D * D * 2);
    ushort* hb        = (ushort*)take((size_t)NN * D * 2);
    float*  x1        = (float*)take((size_t)NN * D * 4);

    const int nBlkN   = (NN + 255) / 256;
    const int nBlkE   = (NE + 255) / 256;
    const int nBlkG   = (NN + 63) / 64;
    const int nBlkAgg = (NN * 64 + 255) / 256;
    const int nBlkW   = (2 * D * D + 255) / 256;

    // CSR build + weight transpose
    k_wt<<<nBlkW, 256, 0, stream>>>(W1, W2, wtb1, wtb2);
    k_init<<<nBlkN, 256, 0, stream>>>(pc, NN);
    k_deg_cnt<<<nBlkE, 256, 0, stream>>>(dst, ew, pc, erank, NE);
    k_scan_part<<<SCAN_NB, 256, 0, stream>>>(pc, blockSums, deg, NN);
    k_scan_mid<<<1, 64, 0, stream>>>(blockSums, blockOffs, SCAN_NB);
    k_scan_add<<<SCAN_NB, 256, 0, stream>>>(pc, blockOffs, rowptr, NN, NE);
    k_scatter<<<nBlkE, 256, 0, stream>>>(src, dst, ew, deg, rowptr, erank, edges, NE);

    // layer 1
    k_gemm<<<nBlkG, 256, 0, stream>>>(x, wtb1, hb, NN);
    k_agg1<<<nBlkAgg, 256, 0, stream>>>(rowptr, edges, deg, hb, b1, x1, NN);

    // layer 2
    k_gemm<<<nBlkG, 256, 0, stream>>>(x1, wtb2, hb, NN);
    k_agg2<<<nBlkAgg, 256, 0, stream>>>(rowptr, edges, deg, hb, x1, b2, out, NN);
}

// Round 7
// 263.563 us; speedup vs baseline: 11.2009x; 1.1630x over previous
//
#include <hip/hip_runtime.h>

#define NN 50000
#define NE 800000
#define D 128
#define SCAN_CH 1024
#define SCAN_NB ((NN + SCAN_CH - 1) / SCAN_CH)  // 49

typedef __attribute__((ext_vector_type(8))) short short8;
typedef __attribute__((ext_vector_type(4))) float f32x4;
typedef unsigned short ushort;
typedef unsigned int uint;
typedef unsigned long long u64;

__device__ inline ushort f2b(float x) {  // f32 -> bf16 RNE
    uint u = __float_as_uint(x);
    return (ushort)((u + 0x7fffu + ((u >> 16) & 1u)) >> 16);
}
__device__ inline float blo(uint u) { return __uint_as_float(u << 16); }
__device__ inline float bhi(uint u) { return __uint_as_float(u & 0xffff0000u); }

// ---------------- init: packed (cnt<<32 | deg_fix24) = 0 ----------------

__global__ __launch_bounds__(256) void k_init(u64* __restrict__ pc, int n) {
    int i = blockIdx.x * 256 + threadIdx.x;
    if (i < n) pc[i] = 0ull;
}

// ---------------- W transpose + bf16 convert: wtb[c][k] = W[k][c] ----------------

__global__ __launch_bounds__(256) void k_wt(const float* __restrict__ W1,
                                            const float* __restrict__ W2,
                                            ushort* __restrict__ wtb1,
                                            ushort* __restrict__ wtb2) {
    int g = blockIdx.x * 256 + threadIdx.x;
    const float* W = (g < D * D) ? W1 : W2;
    ushort* wt = (g < D * D) ? wtb1 : wtb2;
    int idx = (g < D * D) ? g : g - D * D;
    if (g < 2 * D * D) {
        int k = idx >> 7, c = idx & 127;
        wt[c * D + k] = f2b(W[idx]);
    }
}

// ---------------- fused histogram: one 64-bit atomic per edge ----------------

__global__ __launch_bounds__(256) void k_deg_cnt(const int* __restrict__ dst,
                                                 const float* __restrict__ ew,
                                                 u64* __restrict__ pc,
                                                 int* __restrict__ erank, int e) {
    int i = blockIdx.x * 256 + threadIdx.x;
    if (i < e) {
        int d = dst[i];
        uint fx = (uint)(ew[i] * 16777216.0f + 0.5f);
        u64 pack = (1ull << 32) | (u64)fx;
        u64 old = atomicAdd(&pc[d], pack);
        erank[i] = (int)(old >> 32);
    }
}

// ---------------- hierarchical scan; pass 1 materializes rsd[] = rsqrt(deg) ----------------

__global__ __launch_bounds__(256) void k_scan_part(const u64* __restrict__ pc,
                                                   int* __restrict__ blockSums,
                                                   float* __restrict__ rsd, int n) {
    __shared__ int s[256];
    const int tid = threadIdx.x;
    const int base = blockIdx.x * SCAN_CH + tid * 4;
    int c0 = 0, c1 = 0, c2 = 0, c3 = 0;
    const float sc = 1.0f / 16777216.0f;
    if (base + 3 < n) {
        u64 p0 = pc[base + 0], p1 = pc[base + 1], p2 = pc[base + 2], p3 = pc[base + 3];
        c0 = (int)(p0 >> 32); c1 = (int)(p1 >> 32);
        c2 = (int)(p2 >> 32); c3 = (int)(p3 >> 32);
        float4 dv;
        dv.x = rsqrtf(1.0f + (float)(uint)p0 * sc);
        dv.y = rsqrtf(1.0f + (float)(uint)p1 * sc);
        dv.z = rsqrtf(1.0f + (float)(uint)p2 * sc);
        dv.w = rsqrtf(1.0f + (float)(uint)p3 * sc);
        *(float4*)&rsd[base] = dv;
    } else {
        for (int j = 0; j < 4; ++j) {
            if (base + j < n) {
                u64 p = pc[base + j];
                int cj = (int)(p >> 32);
                if (j == 0) c0 = cj; else if (j == 1) c1 = cj; else if (j == 2) c2 = cj; else c3 = cj;
                rsd[base + j] = rsqrtf(1.0f + (float)(uint)p * sc);
            }
        }
    }
    s[tid] = c0 + c1 + c2 + c3;
    __syncthreads();
    for (int off = 1; off < 256; off <<= 1) {
        int v = s[tid];
        int add = (tid >= off) ? s[tid - off] : 0;
        __syncthreads();
        s[tid] = v + add;
        __syncthreads();
    }
    if (tid == 255) blockSums[blockIdx.x] = s[255];
}

__global__ __launch_bounds__(64) void k_scan_mid(const int* __restrict__ blockSums,
                                                 int* __restrict__ blockOffs, int nb) {
    int l = threadIdx.x;
    int v = (l < nb) ? blockSums[l] : 0;
    int inc = v;
#pragma unroll
    for (int off = 1; off < 64; off <<= 1) {
        int u = __shfl_up(inc, off);
        if (l >= off) inc += u;
    }
    if (l < nb) blockOffs[l] = inc - v;
}

__global__ __launch_bounds__(256) void k_scan_add(const u64* __restrict__ pc,
                                                  const int* __restrict__ blockOffs,
                                                  int* __restrict__ rowptr, int n, int e) {
    __shared__ int s[256];
    const int tid = threadIdx.x;
    const int base = blockIdx.x * SCAN_CH + tid * 4;
    int c0 = 0, c1 = 0, c2 = 0, c3 = 0;
    if (base + 3 < n) {
        c0 = (int)(pc[base + 0] >> 32); c1 = (int)(pc[base + 1] >> 32);
        c2 = (int)(pc[base + 2] >> 32); c3 = (int)(pc[base + 3] >> 32);
    } else {
        if (base + 0 < n) c0 = (int)(pc[base + 0] >> 32);
        if (base + 1 < n) c1 = (int)(pc[base + 1] >> 32);
        if (base + 2 < n) c2 = (int)(pc[base + 2] >> 32);
    }
    int tsum = c0 + c1 + c2 + c3;
    s[tid] = tsum;
    __syncthreads();
    for (int off = 1; off < 256; off <<= 1) {
        int v = s[tid];
        int add = (tid >= off) ? s[tid - off] : 0;
        __syncthreads();
        s[tid] = v + add;
        __syncthreads();
    }
    int p = blockOffs[blockIdx.x] + s[tid] - tsum;
    int p0 = p, p1 = p + c0, p2 = p + c0 + c1, p3 = p + c0 + c1 + c2;
    if (base + 3 < n) {
        *(int4*)&rowptr[base] = make_int4(p0, p1, p2, p3);
    } else {
        if (base + 0 < n) rowptr[base + 0] = p0;
        if (base + 1 < n) rowptr[base + 1] = p1;
        if (base + 2 < n) rowptr[base + 2] = p2;
    }
    if (blockIdx.x == 0 && tid == 0) rowptr[n] = e;
}

// ---------------- scatter (atomic-free): packed {src, norm} per edge ----------------

__global__ __launch_bounds__(256) void k_scatter(const int* __restrict__ src,
                                                 const int* __restrict__ dst,
                                                 const float* __restrict__ ew,
                                                 const float* __restrict__ rsd,
                                                 const int* __restrict__ rowptr,
                                                 const int* __restrict__ erank,
                                                 int2* __restrict__ edges, int e) {
    int i = blockIdx.x * 256 + threadIdx.x;
    if (i >= e) return;
    int s = src[i];
    int d = dst[i];
    float nrm = rsd[s] * ew[i] * rsd[d];
    int pos = rowptr[d] + erank[i];
    int2 ev;
    ev.x = s;
    ev.y = __float_as_int(nrm);
    edges[pos] = ev;
}

// ---------------- MFMA GEMM: h(bf16) = A(f32) @ W via wtb(bf16, [c][k]) ----------------

__global__ __launch_bounds__(256) void k_gemm(const float* __restrict__ A,
                                              const ushort* __restrict__ wtb,
                                              ushort* __restrict__ h, int n) {
    __shared__ ushort bounce[4][16][136];
    const int w = threadIdx.x >> 6, l = threadIdx.x & 63;
    const int r = l & 15, hg = l >> 4;
    const int node = blockIdx.x * 64 + w * 16 + r;
    const bool valid = node < n;
    const float* arow = A + (size_t)(valid ? node : 0) * D;

    short8 afr[4];
#pragma unroll
    for (int kk = 0; kk < 4; ++kk) {
        float4 p = *(const float4*)(arow + kk * 32 + hg * 8);
        float4 q = *(const float4*)(arow + kk * 32 + hg * 8 + 4);
        short8 t;
        t[0] = (short)f2b(p.x); t[1] = (short)f2b(p.y);
        t[2] = (short)f2b(p.z); t[3] = (short)f2b(p.w);
        t[4] = (short)f2b(q.x); t[5] = (short)f2b(q.y);
        t[6] = (short)f2b(q.z); t[7] = (short)f2b(q.w);
        afr[kk] = t;
    }

#pragma unroll
    for (int ct = 0; ct < 8; ++ct) {
        f32x4 acc = {0.f, 0.f, 0.f, 0.f};
#pragma unroll
        for (int kk = 0; kk < 4; ++kk) {
            short8 b = *(const short8*)(wtb + (size_t)(ct * 16 + r) * D + kk * 32 + hg * 8);
            acc = __builtin_amdgcn_mfma_f32_16x16x32_bf16(afr[kk], b, acc, 0, 0, 0);
        }
#pragma unroll
        for (int g = 0; g < 4; ++g)
            bounce[w][hg * 4 + g][ct * 16 + r] = f2b(acc[g]);
    }
    __syncthreads();

#pragma unroll
    for (int it = 0; it < 4; ++it) {
        int cid = it * 64 + l;
        int nl = cid >> 4;
        int ch = cid & 15;
        int onode = blockIdx.x * 64 + w * 16 + nl;
        if (onode < n) {
            int4 vv = *(const int4*)&bounce[w][nl][ch * 8];
            *(int4*)(h + (size_t)onode * D + ch * 8) = vv;
        }
    }
}

// ---------------- aggregation: one wave per node, 16-deep pipelined gathers ----------------
// AGG_BODY computes accx/accy = (Ahat h)[v][f..f+1] given rowptr/edges/rsd/hb.

#define AGG_BODY                                                               \
    float rv = rsd[v];                                                         \
    float dinv2 = rv * rv;                                                     \
    uint us = *(const uint*)(hb + (size_t)v * D + f);                          \
    float accx = dinv2 * blo(us);                                              \
    float accy = dinv2 * bhi(us);                                              \
    int beg = rowptr[v], end = rowptr[v + 1];                                  \
    for (int base = beg; base < end; base += 64) {                             \
        int idx = base + lane;                                                 \
        int2 ev = (idx < end) ? edges[idx] : make_int2(v, 0);                  \
        int mm = min(64, end - base);                                          \
        for (int sb = 0; sb < 4; ++sb) {                                       \
            if (sb * 16 >= mm) break;                                          \
            uint u[16];                                                        \
            float ws[16];                                                      \
            _Pragma("unroll")                                                  \
            for (int j = 0; j < 16; ++j) {                                     \
                int s = __builtin_amdgcn_readlane(ev.x, sb * 16 + j);          \
                ws[j] = __uint_as_float((uint)__builtin_amdgcn_readlane(ev.y, sb * 16 + j)); \
                u[j] = *(const uint*)(hb + (size_t)s * D + f);                 \
            }                                                                  \
            _Pragma("unroll")                                                  \
            for (int j = 0; j < 16; ++j) {                                     \
                accx += ws[j] * blo(u[j]);                                     \
                accy += ws[j] * bhi(u[j]);                                     \
            }                                                                  \
        }                                                                      \
    }

__global__ __launch_bounds__(256) void k_agg1(const int* __restrict__ rowptr,
                                              const int2* __restrict__ edges,
                                              const float* __restrict__ rsd,
                                              const ushort* __restrict__ hb,
                                              const float* __restrict__ b,
                                              float* __restrict__ x1, int n) {
    int v = (blockIdx.x * 256 + threadIdx.x) >> 6;
    if (v >= n) return;
    int lane = threadIdx.x & 63;
    int f = lane * 2;
    AGG_BODY
    float2 o;
    o.x = fmaxf(accx + b[f + 0], 0.0f);
    o.y = fmaxf(accy + b[f + 1], 0.0f);
    *(float2*)&x1[(size_t)v * D + f] = o;
}

__global__ __launch_bounds__(256) void k_agg2(const int* __restrict__ rowptr,
                                              const int2* __restrict__ edges,
                                              const float* __restrict__ rsd,
                                              const ushort* __restrict__ hb,
                                              const float* __restrict__ x1,
                                              const float* __restrict__ b,
                                              float* __restrict__ out, int n) {
    int v = (blockIdx.x * 256 + threadIdx.x) >> 6;
    if (v >= n) return;
    int lane = threadIdx.x & 63;
    int f = lane * 2;
    AGG_BODY
    float2 xv = *(const float2*)&x1[(size_t)v * D + f];
    float4 o;
    o.x = xv.x;
    o.y = fmaxf(accx + b[f + 0], 0.0f);
    o.z = xv.y;
    o.w = fmaxf(accy + b[f + 1], 0.0f);
    *(float4*)&out[((size_t)v * D + f) * 2] = o;
}

extern "C" void kernel_launch(void* const* d_in, const int* in_sizes, int n_in,
                              void* d_out, int out_size, void* d_ws, size_t ws_size,
                              hipStream_t stream) {
    const float* x  = (const float*)d_in[0];
    const int*   ei = (const int*)d_in[1];
    const float* ew = (const float*)d_in[2];
    const float* W1 = (const float*)d_in[3];
    const float* b1 = (const float*)d_in[4];
    const float* W2 = (const float*)d_in[5];
    const float* b2 = (const float*)d_in[6];
    float* out = (float*)d_out;

    const int* src = ei;
    const int* dst = ei + NE;

    char* w = (char*)d_ws;
    auto take = [&](size_t bytes) {
        char* p = w;
        w += (bytes + 255) & ~(size_t)255;
        return p;
    };
    u64*    pc        = (u64*)take((size_t)NN * 8);
    float*  rsd       = (float*)take((size_t)NN * 4);
    int*    rowptr    = (int*)take((size_t)(NN + 1) * 4);
    int*    blockSums = (int*)take((size_t)SCAN_NB * 4);
    int*    blockOffs = (int*)take((size_t)SCAN_NB * 4);
    int*    erank     = (int*)take((size_t)NE * 4);
    int2*   edges     = (int2*)take((size_t)NE * 8);
    ushort* wtb1      = (ushort*)take((size_t)D * D * 2);
    ushort* wtb2      = (ushort*)take((size_t)D * D * 2);
    ushort* hb        = (ushort*)take((size_t)NN * D * 2);
    float*  x1        = (float*)take((size_t)NN * D * 4);

    const int nBlkN   = (NN + 255) / 256;
    const int nBlkE   = (NE + 255) / 256;
    const int nBlkG   = (NN + 63) / 64;
    const int nBlkAgg = (NN * 64 + 255) / 256;
    const int nBlkW   = (2 * D * D + 255) / 256;

    // CSR build + weight transpose
    k_wt<<<nBlkW, 256, 0, stream>>>(W1, W2, wtb1, wtb2);
    k_init<<<nBlkN, 256, 0, stream>>>(pc, NN);
    k_deg_cnt<<<nBlkE, 256, 0, stream>>>(dst, ew, pc, erank, NE);
    k_scan_part<<<SCAN_NB, 256, 0, stream>>>(pc, blockSums, rsd, NN);
    k_scan_mid<<<1, 64, 0, stream>>>(blockSums, blockOffs, SCAN_NB);
    k_scan_add<<<SCAN_NB, 256, 0, stream>>>(pc, blockOffs, rowptr, NN, NE);
    k_scatter<<<nBlkE, 256, 0, stream>>>(src, dst, ew, rsd, rowptr, erank, edges, NE);

    // layer 1
    k_gemm<<<nBlkG, 256, 0, stream>>>(x, wtb1, hb, NN);
    k_agg1<<<nBlkAgg, 256, 0, stream>>>(rowptr, edges, rsd, hb, b1, x1, NN);

    // layer 2
    k_gemm<<<nBlkG, 256, 0, stream>>>(x1, wtb2, hb, NN);
    k_agg2<<<nBlkAgg, 256, 0, stream>>>(rowptr, edges, rsd, hb, x1, b2, out, NN);
}

// Round 9
// 257.066 us; speedup vs baseline: 11.4840x; 1.0253x over previous
//
#include <hip/hip_runtime.h>

#define NN 50000
#define NE 800000
#define D 128
#define SCAN_CH 1024
#define SCAN_NB ((NN + SCAN_CH - 1) / SCAN_CH)  // 49

typedef __attribute__((ext_vector_type(8))) short short8;
typedef __attribute__((ext_vector_type(4))) float f32x4;
typedef unsigned short ushort;
typedef unsigned int uint;
typedef unsigned long long u64;

__device__ inline ushort f2b(float x) {  // f32 -> bf16 RNE
    uint u = __float_as_uint(x);
    return (ushort)((u + 0x7fffu + ((u >> 16) & 1u)) >> 16);
}
__device__ inline float blo(uint u) { return __uint_as_float(u << 16); }
__device__ inline float bhi(uint u) { return __uint_as_float(u & 0xffff0000u); }

// ---------------- init pc + W transpose/bf16 (merged) ----------------

__global__ __launch_bounds__(256) void k_init_wt(u64* __restrict__ pc,
                                                 const float* __restrict__ W1,
                                                 const float* __restrict__ W2,
                                                 ushort* __restrict__ wtb1,
                                                 ushort* __restrict__ wtb2, int n) {
    int g = blockIdx.x * 256 + threadIdx.x;
    if (g < n) pc[g] = 0ull;
    if (g < 2 * D * D) {
        const float* W = (g < D * D) ? W1 : W2;
        ushort* wt = (g < D * D) ? wtb1 : wtb2;
        int idx = (g < D * D) ? g : g - D * D;
        int k = idx >> 7, c = idx & 127;
        wt[c * D + k] = f2b(W[idx]);
    }
}

// ---------------- fused histogram: one 64-bit atomic per edge, 4 edges/thread ----------------

__global__ __launch_bounds__(256) void k_deg_cnt(const int* __restrict__ dst,
                                                 const float* __restrict__ ew,
                                                 u64* __restrict__ pc,
                                                 int* __restrict__ erank, int e4) {
    int i = blockIdx.x * 256 + threadIdx.x;
    if (i >= e4) return;
    int4 d4 = *(const int4*)&dst[i * 4];
    float4 w4 = *(const float4*)&ew[i * 4];
    int4 r4;
    {
        uint fx = (uint)(w4.x * 16777216.0f + 0.5f);
        r4.x = (int)(atomicAdd(&pc[d4.x], (1ull << 32) | (u64)fx) >> 32);
    }
    {
        uint fx = (uint)(w4.y * 16777216.0f + 0.5f);
        r4.y = (int)(atomicAdd(&pc[d4.y], (1ull << 32) | (u64)fx) >> 32);
    }
    {
        uint fx = (uint)(w4.z * 16777216.0f + 0.5f);
        r4.z = (int)(atomicAdd(&pc[d4.z], (1ull << 32) | (u64)fx) >> 32);
    }
    {
        uint fx = (uint)(w4.w * 16777216.0f + 0.5f);
        r4.w = (int)(atomicAdd(&pc[d4.w], (1ull << 32) | (u64)fx) >> 32);
    }
    *(int4*)&erank[i * 4] = r4;
}

// ---------------- scan pass 1: block sums + rsd[] = rsqrt(deg) ----------------

__global__ __launch_bounds__(256) void k_scan_part(const u64* __restrict__ pc,
                                                   int* __restrict__ blockSums,
                                                   float* __restrict__ rsd, int n) {
    __shared__ int s[256];
    const int tid = threadIdx.x;
    const int base = blockIdx.x * SCAN_CH + tid * 4;
    int c0 = 0, c1 = 0, c2 = 0, c3 = 0;
    const float sc = 1.0f / 16777216.0f;
    if (base + 3 < n) {
        u64 p0 = pc[base + 0], p1 = pc[base + 1], p2 = pc[base + 2], p3 = pc[base + 3];
        c0 = (int)(p0 >> 32); c1 = (int)(p1 >> 32);
        c2 = (int)(p2 >> 32); c3 = (int)(p3 >> 32);
        float4 dv;
        dv.x = rsqrtf(1.0f + (float)(uint)p0 * sc);
        dv.y = rsqrtf(1.0f + (float)(uint)p1 * sc);
        dv.z = rsqrtf(1.0f + (float)(uint)p2 * sc);
        dv.w = rsqrtf(1.0f + (float)(uint)p3 * sc);
        *(float4*)&rsd[base] = dv;
    } else {
        for (int j = 0; j < 4; ++j) {
            if (base + j < n) {
                u64 p = pc[base + j];
                int cj = (int)(p >> 32);
                if (j == 0) c0 = cj; else if (j == 1) c1 = cj; else if (j == 2) c2 = cj; else c3 = cj;
                rsd[base + j] = rsqrtf(1.0f + (float)(uint)p * sc);
            }
        }
    }
    s[tid] = c0 + c1 + c2 + c3;
    __syncthreads();
    for (int off = 1; off < 256; off <<= 1) {
        int v = s[tid];
        int add = (tid >= off) ? s[tid - off] : 0;
        __syncthreads();
        s[tid] = v + add;
        __syncthreads();
    }
    if (tid == 255) blockSums[blockIdx.x] = s[255];
}

// ---------------- scan pass 2 (mid-scan inlined in wave 0) ----------------

__global__ __launch_bounds__(256) void k_scan_add(const u64* __restrict__ pc,
                                                  const int* __restrict__ blockSums,
                                                  int* __restrict__ rowptr, int n, int e) {
    __shared__ int s[256];
    __shared__ int s_boff;
    const int tid = threadIdx.x;
    // wave 0: exclusive scan of the 49 block sums, keep this block's offset
    if (tid < 64) {
        int v = (tid < SCAN_NB) ? blockSums[tid] : 0;
        int inc = v;
#pragma unroll
        for (int off = 1; off < 64; off <<= 1) {
            int u = __shfl_up(inc, off);
            if (tid >= off) inc += u;
        }
        if (tid == blockIdx.x) s_boff = inc - v;
    }
    const int base = blockIdx.x * SCAN_CH + tid * 4;
    int c0 = 0, c1 = 0, c2 = 0, c3 = 0;
    if (base + 3 < n) {
        c0 = (int)(pc[base + 0] >> 32); c1 = (int)(pc[base + 1] >> 32);
        c2 = (int)(pc[base + 2] >> 32); c3 = (int)(pc[base + 3] >> 32);
    } else {
        if (base + 0 < n) c0 = (int)(pc[base + 0] >> 32);
        if (base + 1 < n) c1 = (int)(pc[base + 1] >> 32);
        if (base + 2 < n) c2 = (int)(pc[base + 2] >> 32);
    }
    int tsum = c0 + c1 + c2 + c3;
    s[tid] = tsum;
    __syncthreads();
    for (int off = 1; off < 256; off <<= 1) {
        int v = s[tid];
        int add = (tid >= off) ? s[tid - off] : 0;
        __syncthreads();
        s[tid] = v + add;
        __syncthreads();
    }
    int p = s_boff + s[tid] - tsum;
    int p0 = p, p1 = p + c0, p2 = p + c0 + c1, p3 = p + c0 + c1 + c2;
    if (base + 3 < n) {
        *(int4*)&rowptr[base] = make_int4(p0, p1, p2, p3);
    } else {
        if (base + 0 < n) rowptr[base + 0] = p0;
        if (base + 1 < n) rowptr[base + 1] = p1;
        if (base + 2 < n) rowptr[base + 2] = p2;
    }
    if (blockIdx.x == 0 && tid == 0) rowptr[n] = e;
}

// ---------------- scatter: pure coalesced reads + one random 8B write ----------------
// edges[pos] = {src, ew}; norm factored into hs-table and per-node rv.

__global__ __launch_bounds__(256) void k_scatter(const int* __restrict__ src,
                                                 const int* __restrict__ dst,
                                                 const float* __restrict__ ew,
                                                 const int* __restrict__ rowptr,
                                                 const int* __restrict__ erank,
                                                 int2* __restrict__ edges, int e) {
    int i = blockIdx.x * 256 + threadIdx.x;
    if (i >= e) return;
    int d = dst[i];
    int pos = rowptr[d] + erank[i];
    int2 ev;
    ev.x = src[i];
    ev.y = __float_as_int(ew[i]);
    edges[pos] = ev;
}

// ---------------- MFMA GEMM: hs(bf16) = rsd-row-scaled (A @ W) ----------------

__global__ __launch_bounds__(256) void k_gemm(const float* __restrict__ A,
                                              const ushort* __restrict__ wtb,
                                              const float* __restrict__ rsd,
                                              ushort* __restrict__ h, int n) {
    __shared__ ushort bounce[4][16][136];
    const int w = threadIdx.x >> 6, l = threadIdx.x & 63;
    const int r = l & 15, hg = l >> 4;
    const int node = blockIdx.x * 64 + w * 16 + r;
    const bool valid = node < n;
    const float* arow = A + (size_t)(valid ? node : 0) * D;

    short8 afr[4];
#pragma unroll
    for (int kk = 0; kk < 4; ++kk) {
        float4 p = *(const float4*)(arow + kk * 32 + hg * 8);
        float4 q = *(const float4*)(arow + kk * 32 + hg * 8 + 4);
        short8 t;
        t[0] = (short)f2b(p.x); t[1] = (short)f2b(p.y);
        t[2] = (short)f2b(p.z); t[3] = (short)f2b(p.w);
        t[4] = (short)f2b(q.x); t[5] = (short)f2b(q.y);
        t[6] = (short)f2b(q.z); t[7] = (short)f2b(q.w);
        afr[kk] = t;
    }

    // rsd for the 4 C-rows this lane writes (row = hg*4+g)
    float rs[4];
#pragma unroll
    for (int g = 0; g < 4; ++g) {
        int nd = blockIdx.x * 64 + w * 16 + hg * 4 + g;
        rs[g] = (nd < n) ? rsd[nd] : 1.0f;
    }

#pragma unroll
    for (int ct = 0; ct < 8; ++ct) {
        f32x4 acc = {0.f, 0.f, 0.f, 0.f};
#pragma unroll
        for (int kk = 0; kk < 4; ++kk) {
            short8 b = *(const short8*)(wtb + (size_t)(ct * 16 + r) * D + kk * 32 + hg * 8);
            acc = __builtin_amdgcn_mfma_f32_16x16x32_bf16(afr[kk], b, acc, 0, 0, 0);
        }
#pragma unroll
        for (int g = 0; g < 4; ++g)
            bounce[w][hg * 4 + g][ct * 16 + r] = f2b(acc[g] * rs[g]);
    }
    __syncthreads();

#pragma unroll
    for (int it = 0; it < 4; ++it) {
        int cid = it * 64 + l;
        int nl = cid >> 4;
        int ch = cid & 15;
        int onode = blockIdx.x * 64 + w * 16 + nl;
        if (onode < n) {
            int4 vv = *(const int4*)&bounce[w][nl][ch * 8];
            *(int4*)(h + (size_t)onode * D + ch * 8) = vv;
        }
    }
}

// ---------------- aggregation: one wave per node, 16-deep pipelined gathers ----------------
// acc = hs[v] + sum_e ew_e * hs[src_e]; result = rv * acc (+bias, relu).

#define AGG_BODY                                                               \
    float rv = rsd[v];                                                         \
    uint us = *(const uint*)(hb + (size_t)v * D + f);                          \
    float accx = blo(us);                                                      \
    float accy = bhi(us);                                                      \
    int beg = rowptr[v], end = rowptr[v + 1];                                  \
    for (int base = beg; base < end; base += 64) {                             \
        int idx = base + lane;                                                 \
        int2 ev = (idx < end) ? edges[idx] : make_int2(v, 0);                  \
        int mm = min(64, end - base);                                          \
        for (int sb = 0; sb < 4; ++sb) {                                       \
            if (sb * 16 >= mm) break;                                          \
            uint u[16];                                                        \
            float ws[16];                                                      \
            _Pragma("unroll")                                                  \
            for (int j = 0; j < 16; ++j) {                                     \
                int s = __builtin_amdgcn_readlane(ev.x, sb * 16 + j);          \
                ws[j] = __uint_as_float((uint)__builtin_amdgcn_readlane(ev.y, sb * 16 + j)); \
                u[j] = *(const uint*)(hb + (size_t)s * D + f);                 \
            }                                                                  \
            _Pragma("unroll")                                                  \
            for (int j = 0; j < 16; ++j) {                                     \
                accx += ws[j] * blo(u[j]);                                     \
                accy += ws[j] * bhi(u[j]);                                     \
            }                                                                  \
        }                                                                      \
    }

__global__ __launch_bounds__(256) void k_agg1(const int* __restrict__ rowptr,
                                              const int2* __restrict__ edges,
                                              const float* __restrict__ rsd,
                                              const ushort* __restrict__ hb,
                                              const float* __restrict__ b,
                                              float* __restrict__ x1, int n) {
    int v = (blockIdx.x * 256 + threadIdx.x) >> 6;
    if (v >= n) return;
    int lane = threadIdx.x & 63;
    int f = lane * 2;
    AGG_BODY
    float2 o;
    o.x = fmaxf(rv * accx + b[f + 0], 0.0f);
    o.y = fmaxf(rv * accy + b[f + 1], 0.0f);
    *(float2*)&x1[(size_t)v * D + f] = o;
}

__global__ __launch_bounds__(256) void k_agg2(const int* __restrict__ rowptr,
                                              const int2* __restrict__ edges,
                                              const float* __restrict__ rsd,
                                              const ushort* __restrict__ hb,
                                              const float* __restrict__ x1,
                                              const float* __restrict__ b,
                                              float* __restrict__ out, int n) {
    int v = (blockIdx.x * 256 + threadIdx.x) >> 6;
    if (v >= n) return;
    int lane = threadIdx.x & 63;
    int f = lane * 2;
    AGG_BODY
    float2 xv = *(const float2*)&x1[(size_t)v * D + f];
    float4 o;
    o.x = xv.x;
    o.y = fmaxf(rv * accx + b[f + 0], 0.0f);
    o.z = xv.y;
    o.w = fmaxf(rv * accy + b[f + 1], 0.0f);
    *(float4*)&out[((size_t)v * D + f) * 2] = o;
}

extern "C" void kernel_launch(void* const* d_in, const int* in_sizes, int n_in,
                              void* d_out, int out_size, void* d_ws, size_t ws_size,
                              hipStream_t stream) {
    const float* x  = (const float*)d_in[0];
    const int*   ei = (const int*)d_in[1];
    const float* ew = (const float*)d_in[2];
    const float* W1 = (const float*)d_in[3];
    const float* b1 = (const float*)d_in[4];
    const float* W2 = (const float*)d_in[5];
    const float* b2 = (const float*)d_in[6];
    float* out = (float*)d_out;

    const int* src = ei;
    const int* dst = ei + NE;

    char* w = (char*)d_ws;
    auto take = [&](size_t bytes) {
        char* p = w;
        w += (bytes + 255) & ~(size_t)255;
        return p;
    };
    u64*    pc        = (u64*)take((size_t)NN * 8);
    float*  rsd       = (float*)take((size_t)NN * 4);
    int*    rowptr    = (int*)take((size_t)(NN + 1) * 4);
    int*    blockSums = (int*)take((size_t)SCAN_NB * 4);
    int*    erank     = (int*)take((size_t)NE * 4);
    int2*   edges     = (int2*)take((size_t)NE * 8);
    ushort* wtb1      = (ushort*)take((size_t)D * D * 2);
    ushort* wtb2      = (ushort*)take((size_t)D * D * 2);
    ushort* hb        = (ushort*)take((size_t)NN * D * 2);
    float*  x1        = (float*)take((size_t)NN * D * 4);

    const int nBlkN   = (NN + 255) / 256;
    const int nBlkE   = (NE + 255) / 256;
    const int nBlkE4  = (NE / 4 + 255) / 256;
    const int nBlkG   = (NN + 63) / 64;
    const int nBlkAgg = (NN * 64 + 255) / 256;

    // CSR build + weight transpose
    k_init_wt<<<nBlkN, 256, 0, stream>>>(pc, W1, W2, wtb1, wtb2, NN);
    k_deg_cnt<<<nBlkE4, 256, 0, stream>>>(dst, ew, pc, erank, NE / 4);
    k_scan_part<<<SCAN_NB, 256, 0, stream>>>(pc, blockSums, rsd, NN);
    k_scan_add<<<SCAN_NB, 256, 0, stream>>>(pc, blockSums, rowptr, NN, NE);
    k_scatter<<<nBlkE, 256, 0, stream>>>(src, dst, ew, rowptr, erank, edges, NE);

    // layer 1
    k_gemm<<<nBlkG, 256, 0, stream>>>(x, wtb1, rsd, hb, NN);
    k_agg1<<<nBlkAgg, 256, 0, stream>>>(rowptr, edges, rsd, hb, b1, x1, NN);

    // layer 2
    k_gemm<<<nBlkG, 256, 0, stream>>>(x1, wtb2, rsd, hb, NN);
    k_agg2<<<nBlkAgg, 256, 0, stream>>>(rowptr, edges, rsd, hb, x1, b2, out, NN);
}